// Round 4
// baseline (459.189 us; speedup 1.0000x reference)
//
#include <hip/hip_runtime.h>

// ChipDetector: gray -> 5x5 gauss -> sobel_y -> |.| -> 5x5 dilate -> bbox of >0.
// Reduced to: bbox of nonzero sobel(blur(gray)) expanded by +-2 (dilation shifts
// bbox by 2; tile scatter-add only ORs positives; per-tile padding only adds
// positives -> global computation gives the same bbox a.s.).
//
// R4: merged separable kernel + deep prefetch, barrier-free.
//   Vertical:  D(y) = [1,4,5,0,-5,-4,-1]/16 over gray rows (gauss (x) sobel_y),
//              with exact boundary corrections at y=0 / y=H-1 reproducing the
//              reference's inter-stage row clipping.
//   Horizontal: E = [1,6,15,20,15,6,1]/16 over D (gauss (x) [1,2,1]), with
//              column corrections at x=0 / x=W-1.
//   Each lane owns 4 cols (float4); 10-row register window; 4 output rows per
//   iteration; next iteration's 12 float4 loads issued before the window is
//   consumed (full-iteration prefetch distance, 192 B/lane in flight).
//   Horizontal halo via __shfl; wave-edge lanes keep a predicated halo group.

constexpr int H = 4096, W = 4096;
constexpr int NT = 256;             // 4 waves per block
constexpr int WCOLS = 256;          // columns per wave (64 lanes x 4)
constexpr int TROWS = 16;           // output rows per wave
constexpr int RPI = 4;              // rows per iteration
constexpr int NITER = TROWS / RPI;  // 4
constexpr int IMAX = 2147483647;

__global__ void init_ws(int* ws) {
    ws[0] = IMAX;  // ymin
    ws[1] = -1;    // ymax
    ws[2] = IMAX;  // xmin
    ws[3] = -1;    // xmax
}

__device__ __forceinline__ float4 f4_zero() { return make_float4(0.f, 0.f, 0.f, 0.f); }

// D = c1*(a0-a6) + c4*(a1-a5) + c5*(a2-a4)
__device__ __forceinline__ float4 vert7(const float4& a0, const float4& a1,
                                        const float4& a2, const float4& a4,
                                        const float4& a5, const float4& a6) {
    constexpr float c1 = 0.0625f, c4 = 0.25f, c5 = 0.3125f;
    return make_float4(
        c1 * (a0.x - a6.x) + c4 * (a1.x - a5.x) + c5 * (a2.x - a4.x),
        c1 * (a0.y - a6.y) + c4 * (a1.y - a5.y) + c5 * (a2.y - a4.y),
        c1 * (a0.z - a6.z) + c4 * (a1.z - a5.z) + c5 * (a2.z - a4.z),
        c1 * (a0.w - a6.w) + c4 * (a1.w - a5.w) + c5 * (a2.w - a4.w));
}

// d += s*a + t*b  (componentwise)
__device__ __forceinline__ void axpy2(float4& d, float s, const float4& a,
                                      float t, const float4& b) {
    d.x += s * a.x + t * b.x;
    d.y += s * a.y + t * b.y;
    d.z += s * a.z + t * b.z;
    d.w += s * a.w + t * b.w;
}

__launch_bounds__(NT, 3)
__global__ void edge_kernel(const float* __restrict__ x,
                            const float* __restrict__ gw,
                            int* __restrict__ ws) {
    __shared__ int s_miny, s_maxy, s_minx, s_maxx;

    const int tid  = threadIdx.x;
    const int lane = tid & 63;
    const int wid  = tid >> 6;

    if (tid == 0) { s_miny = IMAX; s_maxy = -1; s_minx = IMAX; s_maxx = -1; }
    __syncthreads();

    const int wx0 = (blockIdx.x * 4 + wid) * WCOLS;   // wave's column base
    const int y0  = blockIdx.y * TROWS;
    const int cm  = wx0 + lane * 4;                   // lane's first column

    const float w0 = gw[0], w1 = gw[1], w2 = gw[2];
    const float* __restrict__ p0 = x;
    const float* __restrict__ p1 = x + (size_t)H * W;
    const float* __restrict__ p2 = x + 2 * (size_t)H * W;

    // wave-edge halo group: lane 0 -> wx0-4..wx0-1, lane 63 -> wx0+256..+259
    const bool haloL = (lane == 0), haloR = (lane == 63);
    const bool hasx  = haloL | haloR;
    const int  ce    = haloL ? (wx0 - 4) : (wx0 + WCOLS);
    const bool cev   = hasx & (ce >= 0) & (ce < W);

    auto loadg4 = [&](int r, int c, bool valid) -> float4 {
        if (!valid || r < 0 || r >= H) return f4_zero();
        size_t idx = (size_t)r * W + c;
        float4 a = *reinterpret_cast<const float4*>(p0 + idx);
        float4 b = *reinterpret_cast<const float4*>(p1 + idx);
        float4 d = *reinterpret_cast<const float4*>(p2 + idx);
        return make_float4(w0 * a.x + w1 * b.x + w2 * d.x,
                           w0 * a.y + w1 * b.y + w2 * d.y,
                           w0 * a.z + w1 * b.z + w2 * d.z,
                           w0 * a.w + w1 * b.w + w2 * d.w);
    };

    // window g[j] = gray row (yb-3+j), yb = current 4-row block start
    float4 g[10], ge[10];
    #pragma unroll
    for (int j = 0; j < 10; ++j) {
        int r = y0 - 3 + j;
        g[j]  = loadg4(r, cm, true);
        ge[j] = hasx ? loadg4(r, ce, cev) : f4_zero();
    }

    constexpr float m0 = 0.0625f, m1 = 0.375f, m2 = 0.9375f, m3 = 1.25f;

    int gminy = IMAX, gmaxy = -1;
    unsigned hits = 0;   // bit j: column cm+j ever hit

    #pragma unroll
    for (int it = 0; it < NITER; ++it) {
        const int yb = y0 + it * RPI;

        // prefetch rows yb+7..yb+10 for the next iteration (issued before the
        // window is consumed -> full-iteration latency cover)
        float4 nf[4], nef[4];
        if (it + 1 < NITER) {
            #pragma unroll
            for (int j = 0; j < 4; ++j) {
                int r = yb + 7 + j;
                nf[j]  = loadg4(r, cm, true);
                nef[j] = hasx ? loadg4(r, ce, cev) : f4_zero();
            }
        }

        #pragma unroll
        for (int i = 0; i < RPI; ++i) {
            const int y = yb + i;

            float4 D = vert7(g[i], g[i + 1], g[i + 2], g[i + 4], g[i + 5], g[i + 6]);
            float4 De = f4_zero();
            if (hasx)
                De = vert7(ge[i], ge[i + 1], ge[i + 2], ge[i + 4], ge[i + 5], ge[i + 6]);

            // exact row-clip corrections (reference zero-clips blurred rows)
            if (y == 0) {            // e(0) = -S(1): D += -1/4 g(0) - 1/16 g(1)
                axpy2(D, -0.25f, g[i + 3], -0.0625f, g[i + 4]);
                if (hasx) axpy2(De, -0.25f, ge[i + 3], -0.0625f, ge[i + 4]);
            }
            if (y == H - 1) {        // e(H-1) = S(H-2): D += 1/4 g(H-1) + 1/16 g(H-2)
                axpy2(D, 0.25f, g[i + 3], 0.0625f, g[i + 2]);
                if (hasx) axpy2(De, 0.25f, ge[i + 3], 0.0625f, ge[i + 2]);
            }

            // horizontal halo via shuffles (all lanes active)
            float L1 = __shfl_up(D.w, 1);     // col cm-1
            float L2 = __shfl_up(D.z, 1);     // col cm-2
            float L3 = __shfl_up(D.y, 1);     // col cm-3
            float R1 = __shfl_down(D.x, 1);   // col cm+4
            float R2 = __shfl_down(D.y, 1);   // col cm+5
            float R3 = __shfl_down(D.z, 1);   // col cm+6
            if (haloL) { L1 = De.w; L2 = De.z; L3 = De.y; }
            if (haloR) { R1 = De.x; R2 = De.y; R3 = De.z; }

            // a0..a9 = D at cols cm-3 .. cm+6
            const float a0 = L3, a1 = L2, a2 = L1;
            const float a3 = D.x, a4 = D.y, a5 = D.z, a6 = D.w;
            const float a7 = R1, a8 = R2, a9 = R3;

            float Ex = m0 * (a0 + a6) + m1 * (a1 + a5) + m2 * (a2 + a4) + m3 * a3;
            float Ey = m0 * (a1 + a7) + m1 * (a2 + a6) + m2 * (a3 + a5) + m3 * a4;
            float Ez = m0 * (a2 + a8) + m1 * (a3 + a7) + m2 * (a4 + a6) + m3 * a5;
            float Ew = m0 * (a3 + a9) + m1 * (a4 + a8) + m2 * (a5 + a7) + m3 * a6;

            // exact column-clip corrections (phantom blur(-1) / blur(W))
            if (cm == 0)         Ex -= 0.25f * a3 + 0.0625f * a4;
            if (cm + 3 == W - 1) Ew -= 0.25f * a6 + 0.0625f * a5;

            unsigned h = (Ex != 0.f ? 1u : 0u) | (Ey != 0.f ? 2u : 0u)
                       | (Ez != 0.f ? 4u : 0u) | (Ew != 0.f ? 8u : 0u);
            if (h) {
                hits |= h;
                gminy = min(gminy, y);
                gmaxy = y;
            }
        }

        // rotate window by 4 rows
        if (it + 1 < NITER) {
            #pragma unroll
            for (int j = 0; j < 6; ++j) { g[j] = g[j + 4]; ge[j] = ge[j + 4]; }
            #pragma unroll
            for (int j = 0; j < 4; ++j) { g[6 + j] = nf[j]; ge[6 + j] = nef[j]; }
        }
    }

    if (hits) {
        int lminx = cm + __ffs(hits) - 1;
        int lmaxx = cm + (31 - __clz(hits));
        atomicMin(&s_miny, gminy); atomicMax(&s_maxy, gmaxy);
        atomicMin(&s_minx, lminx); atomicMax(&s_maxx, lmaxx);
    }
    __syncthreads();
    if (tid == 0 && s_maxy >= 0) {
        atomicMin(&ws[0], s_miny);
        atomicMax(&ws[1], s_maxy);
        atomicMin(&ws[2], s_minx);
        atomicMax(&ws[3], s_maxx);
    }
}

__global__ void finalize(const int* __restrict__ ws, float* __restrict__ out) {
    int ymin = ws[0], ymax = ws[1], xmin = ws[2], xmax = ws[3];
    if (ymax < 0) {
        out[0] = 0.f; out[1] = 0.f; out[2] = 0.f; out[3] = 0.f;
    } else {
        // dilation by 2 (clipped), then ref's exclusive max (+1)
        out[0] = (float)(xmin - 2 > 0 ? xmin - 2 : 0);
        out[1] = (float)(ymin - 2 > 0 ? ymin - 2 : 0);
        out[2] = (float)((xmax + 2 < W - 1 ? xmax + 2 : W - 1) + 1);
        out[3] = (float)((ymax + 2 < H - 1 ? ymax + 2 : H - 1) + 1);
    }
}

extern "C" void kernel_launch(void* const* d_in, const int* in_sizes, int n_in,
                              void* d_out, int out_size, void* d_ws, size_t ws_size,
                              hipStream_t stream) {
    const float* xp = (const float*)d_in[0];   // (1,3,4096,4096) fp32
    const float* gwp = (const float*)d_in[1];  // (3,) gray weights
    int*   ws  = (int*)d_ws;
    float* out = (float*)d_out;

    init_ws<<<1, 1, 0, stream>>>(ws);
    dim3 grid(W / (4 * WCOLS), H / TROWS);  // 4 x 256 = 1024 blocks, 4096 waves
    edge_kernel<<<grid, NT, 0, stream>>>(xp, gwp, ws);
    finalize<<<1, 1, 0, stream>>>(ws, out);
}

// Round 5
// 409.427 us; speedup vs baseline: 1.1215x; 1.1215x over previous
//
#include <hip/hip_runtime.h>

// ChipDetector: gray -> 5x5 gauss -> sobel_y -> |.| -> 5x5 dilate -> bbox of >0.
// Reduced (verified R1-R4, absmax 0): bbox of nonzero e expanded by +-2, where
//   e = Mx My g,  My = sobel_y o clip_y o gauss_y (c-taps [1,4,5,0,-5,-4,-1]/16),
//                 Mx = sobel_x o clip_x o gauss_x (m-taps [1,6,15,20,15,6,1]/16),
// with exact clip corrections at image borders. Mx and My commute.
//
// R5: output-sensitive 4-way inward scan with device-scope early exit.
//  - mode 0 (ymin): 8-row bands scanned top-down; row y is self-contained:
//    Q(y)=c-taps over gray rows y+-3 (+y-corrections), e=m-taps over x via
//    lane shuffles (+x-corrections). First hit row -> atomicMin(ws[0]) -> break.
//  - mode 1 (ymax): same, bottom-up, atomicMax(ws[1]).
//  - mode 2 (xmin): transposed (P=m-taps over x window, c-taps across lanes=rows),
//    8-col bands scanned left->right, atomicMin(ws[2]).
//  - mode 3 (xmax): right->left, atomicMax(ws[3]).
// Every block polls its coordinate and exits when it can't improve it; polls are
// monotone performance hints only -> correctness independent of dispatch order.
// No LDS, no __syncthreads, shallow register windows (no spills).

constexpr int H = 4096, W = 4096;
constexpr int NT = 256;              // 4 waves
constexpr int BH = 8;                // band thickness (rows or cols)
constexpr int NBAND = H / BH;        // 512
constexpr int NCHUNK = 4;            // 1024-wide chunks of the other axis
constexpr int NBLK = 4 * NBAND * NCHUNK;  // 8192
constexpr int IMAX = 2147483647;

// taps: c = gauss (x) [1,0,-1] ; m = gauss (x) [1,2,1]
constexpr float c1 = 0.0625f, c4 = 0.25f, c5 = 0.3125f;
constexpr float m0 = 0.0625f, m1 = 0.375f, m2 = 0.9375f, m3 = 1.25f;

__global__ void init_ws(int* ws) {
    ws[0] = IMAX;  // ymin
    ws[1] = -1;    // ymax
    ws[2] = IMAX;  // xmin
    ws[3] = -1;    // xmax
}

__device__ __forceinline__ int ld_dev(int* p) {
    return __hip_atomic_load(p, __ATOMIC_RELAXED, __HIP_MEMORY_SCOPE_AGENT);
}

__device__ __forceinline__ float4 f4z() { return make_float4(0.f, 0.f, 0.f, 0.f); }

// ---------------- row scans (ymin DIR=+1 / ymax DIR=-1) ----------------
template <int DIR>
__device__ void rowscan(const float* __restrict__ p0, const float* __restrict__ p1,
                        const float* __restrict__ p2, float w0, float w1, float w2,
                        int s, int chunk, int* __restrict__ ws) {
    int* wsp = (DIR > 0) ? ws + 0 : ws + 1;
    {   int cur = ld_dev(wsp);
        if (DIR > 0) { if (cur <= s) return; } else { if (cur >= s) return; } }

    const int lane = threadIdx.x & 63, wid = threadIdx.x >> 6;
    const int wx0 = chunk * 1024 + wid * 256;
    const int cm  = wx0 + lane * 4;
    const bool haloL = (lane == 0), haloR = (lane == 63);
    const bool hasx  = haloL | haloR;
    const int  ce    = haloL ? (wx0 - 4) : (wx0 + 256);
    const bool cev   = hasx && ce >= 0 && ce < W;

    auto loadg4 = [&](int r, int c, bool valid) -> float4 {
        if (!valid || r < 0 || r >= H) return f4z();
        size_t idx = (size_t)r * W + c;
        float4 a = *reinterpret_cast<const float4*>(p0 + idx);
        float4 b = *reinterpret_cast<const float4*>(p1 + idx);
        float4 d = *reinterpret_cast<const float4*>(p2 + idx);
        return make_float4(w0 * a.x + w1 * b.x + w2 * d.x,
                           w0 * a.y + w1 * b.y + w2 * d.y,
                           w0 * a.z + w1 * b.z + w2 * d.z,
                           w0 * a.w + w1 * b.w + w2 * d.w);
    };

    // window invariant: g[j] = gray row (y + DIR*(j-3)), i.e. row y+d = g[3+DIR*d]
    float4 g[7], ge[7];
    #pragma unroll
    for (int j = 0; j < 7; ++j) {
        int r = s + DIR * (j - 3);
        g[j]  = loadg4(r, cm, true);
        ge[j] = hasx ? loadg4(r, ce, cev) : f4z();
    }

    for (int t = 0; t < BH; ++t) {
        const int y = s + DIR * t;
        if (t) {
            int cur = ld_dev(wsp);
            if (DIR > 0) { if (cur <= y) return; } else { if (cur >= y) return; }
        }

        // Q(y) = c1(g(y-3)-g(y+3)) + c4(g(y-2)-g(y+2)) + c5(g(y-1)-g(y+1))
        const float4 &A0 = g[3 - 3 * DIR], &A1 = g[3 - 2 * DIR], &A2 = g[3 - DIR];
        const float4 &B2 = g[3 + DIR],     &B1 = g[3 + 2 * DIR], &B0 = g[3 + 3 * DIR];
        float4 Q = make_float4(
            c1 * (A0.x - B0.x) + c4 * (A1.x - B1.x) + c5 * (A2.x - B2.x),
            c1 * (A0.y - B0.y) + c4 * (A1.y - B1.y) + c5 * (A2.y - B2.y),
            c1 * (A0.z - B0.z) + c4 * (A1.z - B1.z) + c5 * (A2.z - B2.z),
            c1 * (A0.w - B0.w) + c4 * (A1.w - B1.w) + c5 * (A2.w - B2.w));
        float4 Qe = f4z();
        if (hasx) {
            const float4 &E0 = ge[3 - 3 * DIR], &E1 = ge[3 - 2 * DIR], &E2 = ge[3 - DIR];
            const float4 &F2 = ge[3 + DIR],     &F1 = ge[3 + 2 * DIR], &F0 = ge[3 + 3 * DIR];
            Qe = make_float4(
                c1 * (E0.x - F0.x) + c4 * (E1.x - F1.x) + c5 * (E2.x - F2.x),
                c1 * (E0.y - F0.y) + c4 * (E1.y - F1.y) + c5 * (E2.y - F2.y),
                c1 * (E0.z - F0.z) + c4 * (E1.z - F1.z) + c5 * (E2.z - F2.z),
                c1 * (E0.w - F0.w) + c4 * (E1.w - F1.w) + c5 * (E2.w - F2.w));
        }
        // y-clip corrections (verified R4): row y+1 = g[3+DIR], row y-1 = g[3-DIR]
        if (y == 0) {
            const float4 &C = g[3], &N = g[3 + DIR];
            Q.x -= 0.25f * C.x + 0.0625f * N.x; Q.y -= 0.25f * C.y + 0.0625f * N.y;
            Q.z -= 0.25f * C.z + 0.0625f * N.z; Q.w -= 0.25f * C.w + 0.0625f * N.w;
            if (hasx) {
                const float4 &Ce = ge[3], &Ne = ge[3 + DIR];
                Qe.x -= 0.25f * Ce.x + 0.0625f * Ne.x; Qe.y -= 0.25f * Ce.y + 0.0625f * Ne.y;
                Qe.z -= 0.25f * Ce.z + 0.0625f * Ne.z; Qe.w -= 0.25f * Ce.w + 0.0625f * Ne.w;
            }
        }
        if (y == H - 1) {
            const float4 &C = g[3], &Pv = g[3 - DIR];
            Q.x += 0.25f * C.x + 0.0625f * Pv.x; Q.y += 0.25f * C.y + 0.0625f * Pv.y;
            Q.z += 0.25f * C.z + 0.0625f * Pv.z; Q.w += 0.25f * C.w + 0.0625f * Pv.w;
            if (hasx) {
                const float4 &Ce = ge[3], &Pe = ge[3 - DIR];
                Qe.x += 0.25f * Ce.x + 0.0625f * Pe.x; Qe.y += 0.25f * Ce.y + 0.0625f * Pe.y;
                Qe.z += 0.25f * Ce.z + 0.0625f * Pe.z; Qe.w += 0.25f * Ce.w + 0.0625f * Pe.w;
            }
        }

        // horizontal m-taps via lane shuffles (cols cm-3..cm+6)
        float L1 = __shfl_up(Q.w, 1), L2 = __shfl_up(Q.z, 1), L3 = __shfl_up(Q.y, 1);
        float R1 = __shfl_down(Q.x, 1), R2 = __shfl_down(Q.y, 1), R3 = __shfl_down(Q.z, 1);
        if (haloL) { L1 = Qe.w; L2 = Qe.z; L3 = Qe.y; }
        if (haloR) { R1 = Qe.x; R2 = Qe.y; R3 = Qe.z; }
        const float a0 = L3, a1 = L2, a2 = L1;
        const float a3 = Q.x, a4 = Q.y, a5 = Q.z, a6 = Q.w;
        const float a7 = R1, a8 = R2, a9 = R3;

        float Ex = m0 * (a0 + a6) + m1 * (a1 + a5) + m2 * (a2 + a4) + m3 * a3;
        float Ey = m0 * (a1 + a7) + m1 * (a2 + a6) + m2 * (a3 + a5) + m3 * a4;
        float Ez = m0 * (a2 + a8) + m1 * (a3 + a7) + m2 * (a4 + a6) + m3 * a5;
        float Ew = m0 * (a3 + a9) + m1 * (a4 + a8) + m2 * (a5 + a7) + m3 * a6;
        if (cm == 0)         Ex -= 0.25f * a3 + 0.0625f * a4;   // phantom blur(-1)
        if (cm + 3 == W - 1) Ew -= 0.25f * a6 + 0.0625f * a5;   // phantom blur(W)

        int h = (Ex != 0.f) | (Ey != 0.f) | (Ez != 0.f) | (Ew != 0.f);
        if (__any(h)) {
            if (lane == 0) {
                if (DIR > 0) atomicMin(wsp, y); else atomicMax(wsp, y);
            }
            return;   // rows further in can't improve this coordinate
        }

        if (t + 1 < BH) {
            #pragma unroll
            for (int j = 0; j < 6; ++j) { g[j] = g[j + 1]; ge[j] = ge[j + 1]; }
            int rn = y + 4 * DIR;
            g[6]  = loadg4(rn, cm, true);
            ge[6] = hasx ? loadg4(rn, ce, cev) : f4z();
        }
    }
}

// ---------------- col scans (xmin DIR=+1 / xmax DIR=-1) ----------------
template <int DIR>
__device__ void colscan(const float* __restrict__ p0, const float* __restrict__ p1,
                        const float* __restrict__ p2, float w0, float w1, float w2,
                        int s, int chunk, int* __restrict__ ws) {
    int* wsp = (DIR > 0) ? ws + 2 : ws + 3;
    {   int cur = ld_dev(wsp);
        if (DIR > 0) { if (cur <= s) return; } else { if (cur >= s) return; } }

    const int lane = threadIdx.x & 63, wid = threadIdx.x >> 6;
    const int r0 = chunk * 1024 + wid * 256 + lane * 4;   // lane owns rows r0..r0+3
    const bool haloL = (lane == 0), haloR = (lane == 63);
    const bool hasx  = haloL | haloR;
    const int  re    = haloL ? (r0 - 4) : (r0 + 4);       // 4 halo rows
    const bool rev   = hasx && re >= 0 && re + 3 < H;

    auto loadc = [&](int r, int c) -> float {   // c may be out of image
        if (c < 0 || c >= W) return 0.f;
        size_t idx = (size_t)r * W + c;
        return w0 * p0[idx] + w1 * p1[idx] + w2 * p2[idx];
    };

    // window invariant: g[j][i] = gray(row r0+i, col x + DIR*(j-3))
    float g[7][4], ge[7][4];
    #pragma unroll
    for (int j = 0; j < 7; ++j) {
        int c = s + DIR * (j - 3);
        #pragma unroll
        for (int i = 0; i < 4; ++i) {
            g[j][i]  = loadc(r0 + i, c);
            ge[j][i] = rev ? loadc(re + i, c) : 0.f;
        }
    }

    for (int t = 0; t < BH; ++t) {
        const int xc = s + DIR * t;
        if (t) {
            int cur = ld_dev(wsp);
            if (DIR > 0) { if (cur <= xc) return; } else { if (cur >= xc) return; }
        }

        // P(xc, row) = m-taps over x window (palindromic -> DIR-independent)
        float pm[4], pe[4];
        #pragma unroll
        for (int i = 0; i < 4; ++i) {
            pm[i] = m0 * (g[0][i] + g[6][i]) + m1 * (g[1][i] + g[5][i])
                  + m2 * (g[2][i] + g[4][i]) + m3 * g[3][i];
            pe[i] = m0 * (ge[0][i] + ge[6][i]) + m1 * (ge[1][i] + ge[5][i])
                  + m2 * (ge[2][i] + ge[4][i]) + m3 * ge[3][i];
            // x-clip corrections: col xc+1 = g[3+DIR], col xc-1 = g[3-DIR]
            if (xc == 0) {
                pm[i] -= 0.25f * g[3][i] + 0.0625f * g[3 + DIR][i];
                pe[i] -= 0.25f * ge[3][i] + 0.0625f * ge[3 + DIR][i];
            }
            if (xc == W - 1) {
                pm[i] -= 0.25f * g[3][i] + 0.0625f * g[3 - DIR][i];
                pe[i] -= 0.25f * ge[3][i] + 0.0625f * ge[3 - DIR][i];
            }
        }

        // c-taps across rows (lane direction); a[k] = P(row r0-3+k)
        float L1 = __shfl_up(pm[3], 1), L2 = __shfl_up(pm[2], 1), L3 = __shfl_up(pm[1], 1);
        float R1 = __shfl_down(pm[0], 1), R2 = __shfl_down(pm[1], 1), R3 = __shfl_down(pm[2], 1);
        if (haloL) { L1 = pe[3]; L2 = pe[2]; L3 = pe[1]; }
        if (haloR) { R1 = pe[0]; R2 = pe[1]; R3 = pe[2]; }
        float a[10] = { L3, L2, L1, pm[0], pm[1], pm[2], pm[3], R1, R2, R3 };

        int h = 0;
        #pragma unroll
        for (int i = 0; i < 4; ++i) {
            float e = c1 * (a[i] - a[i + 6]) + c4 * (a[i + 1] - a[i + 5])
                    + c5 * (a[i + 2] - a[i + 4]);
            const int rr = r0 + i;
            if (rr == 0)     e -= 0.25f * a[i + 3] + 0.0625f * a[i + 4];  // phantom row -1
            if (rr == H - 1) e += 0.25f * a[i + 3] + 0.0625f * a[i + 2];  // phantom row H
            h |= (e != 0.f);
        }
        if (__any(h)) {
            if (lane == 0) {
                if (DIR > 0) atomicMin(wsp, xc); else atomicMax(wsp, xc);
            }
            return;
        }

        if (t + 1 < BH) {
            #pragma unroll
            for (int j = 0; j < 6; ++j)
                #pragma unroll
                for (int i = 0; i < 4; ++i) { g[j][i] = g[j + 1][i]; ge[j][i] = ge[j + 1][i]; }
            int cn = xc + 4 * DIR;
            #pragma unroll
            for (int i = 0; i < 4; ++i) {
                g[6][i]  = loadc(r0 + i, cn);
                ge[6][i] = rev ? loadc(re + i, cn) : 0.f;
            }
        }
    }
}

__launch_bounds__(NT)
__global__ void edge_scan(const float* __restrict__ x,
                          const float* __restrict__ gw,
                          int* __restrict__ ws) {
    // interleave modes so the 16 "decider" blocks (ord 0 of each mode) dispatch first
    const int mode  = blockIdx.x & 3;
    const int local = blockIdx.x >> 2;
    const int chunk = local & 3;
    const int ord   = local >> 2;       // 0..511, band index from the scanned edge

    const float w0 = gw[0], w1 = gw[1], w2 = gw[2];
    const float* p0 = x;
    const float* p1 = x + (size_t)H * W;
    const float* p2 = x + 2 * (size_t)H * W;

    if (mode == 0)      rowscan<+1>(p0, p1, p2, w0, w1, w2, ord * BH,          chunk, ws);
    else if (mode == 1) rowscan<-1>(p0, p1, p2, w0, w1, w2, H - 1 - ord * BH,  chunk, ws);
    else if (mode == 2) colscan<+1>(p0, p1, p2, w0, w1, w2, ord * BH,          chunk, ws);
    else                colscan<-1>(p0, p1, p2, w0, w1, w2, W - 1 - ord * BH,  chunk, ws);
}

__global__ void finalize(const int* __restrict__ ws, float* __restrict__ out) {
    int ymin = ws[0], ymax = ws[1], xmin = ws[2], xmax = ws[3];
    if (ymax < 0) {
        out[0] = 0.f; out[1] = 0.f; out[2] = 0.f; out[3] = 0.f;
    } else {
        // dilation by 2 (clipped), then ref's exclusive max (+1)
        out[0] = (float)(xmin - 2 > 0 ? xmin - 2 : 0);
        out[1] = (float)(ymin - 2 > 0 ? ymin - 2 : 0);
        out[2] = (float)((xmax + 2 < W - 1 ? xmax + 2 : W - 1) + 1);
        out[3] = (float)((ymax + 2 < H - 1 ? ymax + 2 : H - 1) + 1);
    }
}

extern "C" void kernel_launch(void* const* d_in, const int* in_sizes, int n_in,
                              void* d_out, int out_size, void* d_ws, size_t ws_size,
                              hipStream_t stream) {
    const float* xp = (const float*)d_in[0];   // (1,3,4096,4096) fp32
    const float* gw = (const float*)d_in[1];   // (3,) gray weights
    int*   ws  = (int*)d_ws;
    float* out = (float*)d_out;

    init_ws<<<1, 1, 0, stream>>>(ws);
    edge_scan<<<NBLK, NT, 0, stream>>>(xp, gw, ws);
    finalize<<<1, 1, 0, stream>>>(ws, out);
}

// Round 6
// 380.225 us; speedup vs baseline: 1.2077x; 1.0768x over previous
//
#include <hip/hip_runtime.h>

// ChipDetector: gray -> 5x5 gauss -> sobel_y -> |.| -> 5x5 dilate -> bbox of >0.
// Reduced (verified R1-R5, absmax 0): bbox of nonzero e expanded by +-2, where
// e(y) = S(y-1) - S(y+1), S = row-clipped sobel_x(gauss_x(gauss_y(gray))) with
// exact border corrections reproducing the reference's inter-stage zero padding.
//
// R6 = R3 structure (verified math: 5-row register window + S delay line,
// shuffle-based x halo, edge lanes own a predicated halo column-group) with:
//   - TROWS 16 -> 8: grid 2048 blocks = 8192 waves (fills all 32 waves/CU slots)
//   - prefetch depth 2: rows yv+4 and yv+5 in flight; the row consumed by the
//     window rotate was issued two iterations ago -> vmcnt wait never drains
//     the queue (R4 lesson: no __launch_bounds__ min-wave cap -> no spills)
// No LDS in the hot loop, no __syncthreads, waves free-run.

constexpr int H = 4096, W = 4096;
constexpr int NT = 256;             // 4 waves per block
constexpr int WCOLS = 256;          // columns per wave (64 lanes x 4)
constexpr int TROWS = 8;            // output rows per wave
constexpr int IMAX = 2147483647;

__global__ void init_ws(int* ws) {
    ws[0] = IMAX;  // ymin
    ws[1] = -1;    // ymax
    ws[2] = IMAX;  // xmin
    ws[3] = -1;    // xmax
}

__device__ __forceinline__ float4 f4z() { return make_float4(0.f, 0.f, 0.f, 0.f); }

__global__ void edge_kernel(const float* __restrict__ x,
                            const float* __restrict__ gw,
                            int* __restrict__ ws) {
    __shared__ int s_miny, s_maxy, s_minx, s_maxx;

    const int tid  = threadIdx.x;
    const int lane = tid & 63;
    const int wid  = tid >> 6;

    if (tid == 0) { s_miny = IMAX; s_maxy = -1; s_minx = IMAX; s_maxx = -1; }
    __syncthreads();

    const int wx0 = (blockIdx.x * 4 + wid) * WCOLS;   // wave's column base
    const int y0  = blockIdx.y * TROWS;
    const int cm  = wx0 + lane * 4;                   // lane's first column

    const float w0 = gw[0], w1 = gw[1], w2 = gw[2];
    const float* __restrict__ p0 = x;
    const float* __restrict__ p1 = x + (size_t)H * W;
    const float* __restrict__ p2 = x + 2 * (size_t)H * W;

    // wave-edge halo group: lane 0 -> wx0-4..wx0-1, lane 63 -> wx0+256..+259
    const bool haloL = (lane == 0), haloR = (lane == 63);
    const bool hasx  = haloL | haloR;
    const int  ce    = haloL ? (wx0 - 4) : (wx0 + WCOLS);
    const bool cev   = hasx && ce >= 0 && ce < W;

    auto loadg4 = [&](int r, int c, bool valid) -> float4 {
        if (!valid || r < 0 || r >= H) return f4z();
        size_t idx = (size_t)r * W + c;
        float4 a = *reinterpret_cast<const float4*>(p0 + idx);
        float4 b = *reinterpret_cast<const float4*>(p1 + idx);
        float4 d = *reinterpret_cast<const float4*>(p2 + idx);
        return make_float4(w0 * a.x + w1 * b.x + w2 * d.x,
                           w0 * a.y + w1 * b.y + w2 * d.y,
                           w0 * a.z + w1 * b.z + w2 * d.z,
                           w0 * a.w + w1 * b.w + w2 * d.w);
    };

    // 5-row window: g[j] = gray row (yv-2+j) for the current yv
    float4 g[5], ge[5];
    #pragma unroll
    for (int j = 0; j < 5; ++j) {
        int r = y0 - 3 + j;
        g[j]  = loadg4(r, cm, true);
        ge[j] = hasx ? loadg4(r, ce, cev) : f4z();
    }
    // prefetch pipeline: f0 = row yv+3, f1 = row yv+4 (for yv = y0-1)
    float4 f0  = loadg4(y0 + 2, cm, true);
    float4 f1  = loadg4(y0 + 3, cm, true);
    float4 fe0 = hasx ? loadg4(y0 + 2, ce, cev) : f4z();
    float4 fe1 = hasx ? loadg4(y0 + 3, ce, cev) : f4z();

    // vertical gauss [1,4,6,4,1]/16 ; horizontal composite gauss*[1,2,1] taps
    constexpr float k0 = 0.0625f, k1 = 0.25f, k2 = 0.375f;
    constexpr float m0 = 0.0625f, m1 = 0.375f, m2 = 0.9375f, m3 = 1.25f;

    float4 sm1 = f4z(), sm2 = f4z();   // S(yv-1), S(yv-2)
    int gminy = IMAX, gmaxy = -1;
    unsigned hits = 0;                  // bit j: column cm+j ever hit

    #pragma unroll
    for (int it = 0; it < TROWS + 2; ++it) {
        const int yv = y0 - 1 + it;

        // issue prefetch for row yv+5 (consumed two iterations from now)
        float4 f2 = f4z(), fe2 = f4z();
        if (it <= TROWS - 2) {          // last needed row is y0+TROWS+2
            f2 = loadg4(yv + 5, cm, true);
            if (hasx) fe2 = loadg4(yv + 5, ce, cev);
        }

        float4 S = f4z();
        if (yv >= 0 && yv < H) {   // wave-uniform branch (shuffles inside are safe)
            // vertical gauss for row yv (g[] holds rows yv-2..yv+2)
            float4 vg = make_float4(
                k0 * (g[0].x + g[4].x) + k1 * (g[1].x + g[3].x) + k2 * g[2].x,
                k0 * (g[0].y + g[4].y) + k1 * (g[1].y + g[3].y) + k2 * g[2].y,
                k0 * (g[0].z + g[4].z) + k1 * (g[1].z + g[3].z) + k2 * g[2].z,
                k0 * (g[0].w + g[4].w) + k1 * (g[1].w + g[3].w) + k2 * g[2].w);

            // x halo via intra-wave shuffles
            float L1 = __shfl_up(vg.w, 1);     // col cm-1
            float L2 = __shfl_up(vg.z, 1);     // col cm-2
            float L3 = __shfl_up(vg.y, 1);     // col cm-3
            float R1 = __shfl_down(vg.x, 1);   // col cm+4
            float R2 = __shfl_down(vg.y, 1);   // col cm+5
            float R3 = __shfl_down(vg.z, 1);   // col cm+6
            if (hasx) {
                float ve_x = k0 * (ge[0].x + ge[4].x) + k1 * (ge[1].x + ge[3].x) + k2 * ge[2].x;
                float ve_y = k0 * (ge[0].y + ge[4].y) + k1 * (ge[1].y + ge[3].y) + k2 * ge[2].y;
                float ve_z = k0 * (ge[0].z + ge[4].z) + k1 * (ge[1].z + ge[3].z) + k2 * ge[2].z;
                float ve_w = k0 * (ge[0].w + ge[4].w) + k1 * (ge[1].w + ge[3].w) + k2 * ge[2].w;
                if (haloL) { L1 = ve_w; L2 = ve_z; L3 = ve_y; }
                else       { R1 = ve_x; R2 = ve_y; R3 = ve_z; }
            }

            // a0..a9 = vg at cols cm-3 .. cm+6
            const float a0 = L3, a1 = L2, a2 = L1;
            const float a3 = vg.x, a4 = vg.y, a5 = vg.z, a6 = vg.w;
            const float a7 = R1, a8 = R2, a9 = R3;

            S.x = m0 * (a0 + a6) + m1 * (a1 + a5) + m2 * (a2 + a4) + m3 * a3;
            S.y = m0 * (a1 + a7) + m1 * (a2 + a6) + m2 * (a3 + a5) + m3 * a4;
            S.z = m0 * (a2 + a8) + m1 * (a3 + a7) + m2 * (a4 + a6) + m3 * a5;
            S.w = m0 * (a3 + a9) + m1 * (a4 + a8) + m2 * (a5 + a7) + m3 * a6;

            // reference zero-clips blurred at image columns before sobel_x:
            if (cm == 0)         S.x -= 0.25f * a3 + 0.0625f * a4;  // phantom blur(-1)
            if (cm + 3 == W - 1) S.w -= 0.25f * a6 + 0.0625f * a5;  // phantom blur(W)
        }

        // vertical sobel [1,0,-1] with row-clipped S: e(yv-1) = S(yv-2) - S(yv)
        if (it >= 2) {
            const int yy = yv - 1;
            unsigned h = (sm2.x != S.x ? 1u : 0u) | (sm2.y != S.y ? 2u : 0u)
                       | (sm2.z != S.z ? 4u : 0u) | (sm2.w != S.w ? 8u : 0u);
            if (h) {
                hits |= h;
                gminy = min(gminy, yy);
                gmaxy = yy;
            }
        }
        sm2 = sm1; sm1 = S;

        // rotate window; consume f0 (issued two iterations ago)
        g[0] = g[1]; g[1] = g[2]; g[2] = g[3]; g[3] = g[4]; g[4] = f0;
        f0 = f1; f1 = f2;
        if (hasx) {
            ge[0] = ge[1]; ge[1] = ge[2]; ge[2] = ge[3]; ge[3] = ge[4]; ge[4] = fe0;
            fe0 = fe1; fe1 = fe2;
        }
    }

    if (hits) {
        int lminx = cm + __ffs(hits) - 1;
        int lmaxx = cm + (31 - __clz(hits));
        atomicMin(&s_miny, gminy); atomicMax(&s_maxy, gmaxy);
        atomicMin(&s_minx, lminx); atomicMax(&s_maxx, lmaxx);
    }
    __syncthreads();
    if (tid == 0 && s_maxy >= 0) {
        atomicMin(&ws[0], s_miny);
        atomicMax(&ws[1], s_maxy);
        atomicMin(&ws[2], s_minx);
        atomicMax(&ws[3], s_maxx);
    }
}

__global__ void finalize(const int* __restrict__ ws, float* __restrict__ out) {
    int ymin = ws[0], ymax = ws[1], xmin = ws[2], xmax = ws[3];
    if (ymax < 0) {
        out[0] = 0.f; out[1] = 0.f; out[2] = 0.f; out[3] = 0.f;
    } else {
        // dilation by 2 (clipped), then ref's exclusive max (+1)
        out[0] = (float)(xmin - 2 > 0 ? xmin - 2 : 0);
        out[1] = (float)(ymin - 2 > 0 ? ymin - 2 : 0);
        out[2] = (float)((xmax + 2 < W - 1 ? xmax + 2 : W - 1) + 1);
        out[3] = (float)((ymax + 2 < H - 1 ? ymax + 2 : H - 1) + 1);
    }
}

extern "C" void kernel_launch(void* const* d_in, const int* in_sizes, int n_in,
                              void* d_out, int out_size, void* d_ws, size_t ws_size,
                              hipStream_t stream) {
    const float* xp = (const float*)d_in[0];   // (1,3,4096,4096) fp32
    const float* gw = (const float*)d_in[1];   // (3,) gray weights
    int*   ws  = (int*)d_ws;
    float* out = (float*)d_out;

    init_ws<<<1, 1, 0, stream>>>(ws);
    dim3 grid(W / (4 * WCOLS), H / TROWS);  // 4 x 512 = 2048 blocks, 8192 waves
    edge_kernel<<<grid, NT, 0, stream>>>(xp, gw, ws);
    finalize<<<1, 1, 0, stream>>>(ws, out);
}